// Round 12
// baseline (1434.916 us; speedup 1.0000x reference)
//
#include <hip/hip_runtime.h>
#include <hip/hip_bf16.h>
#include <cstdint>
#include <cstddef>

// ============================================================================
// EchoStateNetwork: h_{t+1} = 0.5*tanh(h_t @ W + U[t]) + 0.5*h_t
// U precomputed via 3-term bf16 MFMA GEMM (prep_u2). Persistent 256-WG scan,
// 8 independent row-groups, XCD-local protocol (R9/R11-proven).
// R12: the out[] nt-store is DEFERRED to the top of the next step, issued
// after h-loads+U-prefetch (FIFO [h x8, U, out]), so no poll/drain vmcnt(0)
// ever waits on an HBM write ack. sched_barrier pins the issue order.
//
// ws layout:
//   Whi [1024 n][1024 k] bf16                                   2 MB
//   U   [512 t][32 b][1024 n] f32                              64 MB
//   Hb2 [2][128 row][1024 col] bf16                           512 KB
//   bar census[8]/cb/claim[8] (256B apart) + flag lines        16 KB
// ============================================================================

typedef unsigned short u16;
typedef unsigned int   u32;
typedef unsigned long long u64;
typedef __bf16 bf16x8 __attribute__((ext_vector_type(8)));
typedef u64    u64x2  __attribute__((ext_vector_type(2)));
typedef float  f32x4  __attribute__((ext_vector_type(4)));
typedef float  f32x2  __attribute__((ext_vector_type(2)));

#define T_STEPS 512
#define NWG     256
#define TPB     256

#define OFF_WHI 0
#define OFF_U   (2*1024*1024)
#define OFF_HB  (OFF_U + (size_t)512*32*1024*4)
#define HB_BYTES ((size_t)128*2048)             // 256 KB per buffer
#define OFF_BAR (OFF_HB + 2*HB_BYTES)
// bar (u32 idx): census[x]=x*64, cb=512, claim[x]=(9+x)*64, flags[g]=2048+g*64

__device__ __forceinline__ u16 f2bf(float f) {
  u32 u = __builtin_bit_cast(u32, f);
  u += 0x7fffu + ((u >> 16) & 1u);          // RNE
  return (u16)(u >> 16);
}
__device__ __forceinline__ float bf2f(u16 h) {
  u32 u = ((u32)h) << 16;
  return __builtin_bit_cast(float, u);
}
__device__ __forceinline__ void pinv(bf16x8& v) { asm volatile("" : "+v"(v)); }

__device__ __forceinline__ u32 AADD(u32* p, u32 v) {
  return __hip_atomic_fetch_add(p, v, __ATOMIC_RELAXED, __HIP_MEMORY_SCOPE_AGENT);
}
__device__ __forceinline__ u32 ALD(const u32* p) {
  return __hip_atomic_load(p, __ATOMIC_RELAXED, __HIP_MEMORY_SCOPE_AGENT);
}
__device__ __forceinline__ u64 ALD64(const u64* p) {
  return __hip_atomic_load(p, __ATOMIC_RELAXED, __HIP_MEMORY_SCOPE_AGENT);
}
__device__ __forceinline__ void AST(u32* p, u32 v) {
  __hip_atomic_store(p, v, __ATOMIC_RELAXED, __HIP_MEMORY_SCOPE_AGENT);
}

// --- prep: Whi[n][k] = bf16(W[k][n]) ----------------------------------------
__global__ void prep_w(const float* __restrict__ W, u16* __restrict__ whi) {
  int n = blockIdx.y;
  int k = blockIdx.x * 256 + threadIdx.x;
  whi[n * 1024 + k] = f2bf(W[k * 1024 + n]);
}

// --- prep_u2: U[m=t*32+b][n] = sum_k A[m][k]*Wi[n][k], 3-term bf16 MFMA ----
__global__ void __launch_bounds__(256) prep_u2(const float* __restrict__ x,
                                               const float* __restrict__ Wi,
                                               float* __restrict__ U) {
  __shared__ __align__(16) u16 Ah[128 * 128];   // 32 KB, XOR-swizzled
  __shared__ __align__(16) u16 Al[128 * 128];   // 32 KB
  const int tid = threadIdx.x;
  const int m0 = blockIdx.x << 7;
  const int n0 = blockIdx.y << 7;
  const int wv = tid >> 6, lane = tid & 63;
  const int fc = lane & 15, kb = lane >> 4;

  f32x4 acc[8][2];
#pragma unroll
  for (int mt = 0; mt < 8; ++mt) {
    acc[mt][0] = (f32x4){0.f, 0.f, 0.f, 0.f};
    acc[mt][1] = (f32x4){0.f, 0.f, 0.f, 0.f};
  }

  for (int hf = 0; hf < 2; ++hf) {
    __syncthreads();
#pragma unroll
    for (int s = 0; s < 16; ++s) {
      int f = (s << 8) + tid;
      int row = f >> 5, v = f & 31;
      int cl = v >> 4, i4 = (v & 15) << 2;
      int b = row & 31, t = (m0 + row) >> 5;
      float4 xv = *(const float4*)(x +
          ((size_t)((b << 2) | ((hf << 1) | cl)) * 512 + t) * 64 + i4);
      int byte = (row << 8) + (((cl << 7) + (i4 << 1)) ^ ((row & 7) << 4));
      u16* ph = (u16*)((char*)Ah + byte);
      u16* pl = (u16*)((char*)Al + byte);
      float vv[4] = {xv.x, xv.y, xv.z, xv.w};
#pragma unroll
      for (int e = 0; e < 4; ++e) {
        u16 hh = f2bf(vv[e]);
        ph[e] = hh;
        pl[e] = f2bf(vv[e] - bf2f(hh));
      }
    }
    bf16x8 Bh[2][4], Bl[2][4];
#pragma unroll
    for (int nt = 0; nt < 2; ++nt) {
      const float* wrow = Wi + (size_t)(n0 + (wv << 5) + (nt << 4) + fc) * 256;
#pragma unroll
      for (int kt = 0; kt < 4; ++kt) {
        int k = (hf << 7) + (kt << 5) + (kb << 3);
        float tmp[8];
        *(float4*)&tmp[0] = *(const float4*)(wrow + k);
        *(float4*)&tmp[4] = *(const float4*)(wrow + k + 4);
#pragma unroll
        for (int e = 0; e < 8; ++e) {
          u16 hh = f2bf(tmp[e]);
          Bh[nt][kt][e] = __builtin_bit_cast(__bf16, hh);
          Bl[nt][kt][e] = __builtin_bit_cast(__bf16, f2bf(tmp[e] - bf2f(hh)));
        }
      }
    }
    __syncthreads();
#pragma unroll
    for (int kt = 0; kt < 4; ++kt) {
      int kbyte = (kt << 6) + (kb << 4);
#pragma unroll
      for (int mt = 0; mt < 8; ++mt) {
        int row = (mt << 4) + fc;
        int byte = (row << 8) + (kbyte ^ ((row & 7) << 4));
        bf16x8 ah = *(const bf16x8*)((char*)Ah + byte);
        bf16x8 al = *(const bf16x8*)((char*)Al + byte);
#pragma unroll
        for (int nt = 0; nt < 2; ++nt) {
          acc[mt][nt] = __builtin_amdgcn_mfma_f32_16x16x32_bf16(ah, Bh[nt][kt], acc[mt][nt], 0, 0, 0);
          acc[mt][nt] = __builtin_amdgcn_mfma_f32_16x16x32_bf16(al, Bh[nt][kt], acc[mt][nt], 0, 0, 0);
          acc[mt][nt] = __builtin_amdgcn_mfma_f32_16x16x32_bf16(ah, Bl[nt][kt], acc[mt][nt], 0, 0, 0);
        }
      }
    }
  }
#pragma unroll
  for (int mt = 0; mt < 8; ++mt) {
    int mbase = m0 + (mt << 4) + (kb << 2);
    int n = n0 + (wv << 5) + fc;
#pragma unroll
    for (int nt = 0; nt < 2; ++nt)
#pragma unroll
      for (int r = 0; r < 4; ++r)
        U[(size_t)(mbase + r) * 1024 + n + (nt << 4)] = acc[mt][nt][r];
  }
}

// --- the scan ---------------------------------------------------------------
__global__ void __launch_bounds__(TPB, 1) esn_scan(
    const u16* __restrict__ Whi, const float* __restrict__ U,
    u16* __restrict__ Hb, float* __restrict__ out, u32* __restrict__ bar) {
  __shared__ __align__(16) float red[8 * 64 * 4];   // 8 KB
  __shared__ int sh_q, sh_j, sh_loc;

  const int tid = threadIdx.x;
  const int wv = tid >> 6, lane = tid & 63;
  const int mcol = lane & 15, kb = lane >> 4;

  // ---- census + role claim -------------------------------------------------
  if (tid == 0) {
    int xcd;
    asm volatile("s_getreg_b32 %0, hwreg(HW_REG_XCC_ID)" : "=s"(xcd));
    xcd &= 7;
    AADD(bar + xcd * 64, 1u);
    AADD(bar + 512, 1u);
    while (ALD(bar + 512) < (u32)NWG) __builtin_amdgcn_s_sleep(2);
    bool uni = true;
    for (int k = 0; k < 8; ++k) uni &= (ALD(bar + k * 64) == 32u);
    if (uni) {
      sh_q = xcd;
      sh_j = (int)AADD(bar + (9 + xcd) * 64, 1u);
      sh_loc = 1;
    } else {
      sh_q = blockIdx.x & 7;
      sh_j = blockIdx.x >> 3;
      sh_loc = 0;
    }
  }
  __syncthreads();
  const int q = sh_q, j = sh_j;
  const bool xlocal = (sh_loc != 0);
  const int r0 = q << 4, c0 = j << 5;

  // ---- W fragments: [ntile 2][kt 8] = 64 VGPRs, pinned --------------------
  bf16x8 bh[2][8];
#pragma unroll
  for (int nt = 0; nt < 2; ++nt) {
    const char* wb = (const char*)Whi + (size_t)(c0 + nt * 16 + mcol) * 2048
                     + wv * 512 + kb * 16;
#pragma unroll
    for (int kt = 0; kt < 8; ++kt)
      bh[nt][kt] = *(const bf16x8*)(wb + kt * 64);
  }
#pragma unroll
  for (int nt = 0; nt < 2; ++nt)
#pragma unroll
    for (int kt = 0; kt < 8; ++kt) pinv(bh[nt][kt]);

  // ---- per-thread output mapping ------------------------------------------
  const int row_l = tid >> 4;               // 0..15
  const int col0  = (tid & 15) * 2;         // 0..30
  const int grow  = r0 + row_l;
  const int ont   = col0 >> 4, oci = col0 & 15;
  const int okb   = row_l >> 2, orr = row_l & 3;
  u32* flags = bar + 2048 + q * 64;         // one 128B line per group

  float hreg[2] = {0.f, 0.f};
  float po0 = 0.f, po1 = 0.f;               // deferred out values (step t-1)
  f32x2 uf = *(const f32x2*)(U + (size_t)(grow >> 2) * 1024 + c0 + col0);

  for (int t = 0; t < T_STEPS; ++t) {
    // ---- top: issue h-loads (oldest), U(t+1) prefetch, then out(t-1) -------
    const char* hsrc = (const char*)Hb + (size_t)(t & 1) * HB_BYTES
                       + (size_t)(r0 + mcol) * 2048 + wv * 512 + kb * 16;
    bf16x8 av[8];
    if (xlocal) {
#pragma unroll
      for (int kt = 0; kt < 8; ++kt)
        av[kt] = *(const bf16x8*)(hsrc + kt * 64);    // plain: L2-local, dedup
    } else {
#pragma unroll
      for (int kt = 0; kt < 8; ++kt) {
        u64x2 p;
        p.x = ALD64((const u64*)(hsrc + kt * 64));
        p.y = ALD64((const u64*)(hsrc + kt * 64 + 8));
        av[kt] = __builtin_bit_cast(bf16x8, p);
      }
    }
    f32x2 ufn = uf;
    if (t < T_STEPS - 1)
      ufn = *(const f32x2*)(U + ((size_t)(t + 1) * 32 + (grow >> 2)) * 1024 + c0 + col0);
    __builtin_amdgcn_sched_barrier(0);
    if (t > 0) {      // deferred out-store: drained only at h-drain, aged
      f32x2 o2; o2.x = po0; o2.y = po1;
      __builtin_nontemporal_store(o2,
          (f32x2*)(out + ((size_t)grow * 512 + (t - 1)) * 1024 + c0 + col0));
    }
    __builtin_amdgcn_sched_barrier(0);

    // ---- z = h @ W ----------------------------------------------------------
    f32x4 acc0 = {0.f, 0.f, 0.f, 0.f};
    f32x4 acc1 = {0.f, 0.f, 0.f, 0.f};
#pragma unroll
    for (int kt = 0; kt < 8; ++kt) {
      acc0 = __builtin_amdgcn_mfma_f32_16x16x32_bf16(av[kt], bh[0][kt], acc0, 0, 0, 0);
      acc1 = __builtin_amdgcn_mfma_f32_16x16x32_bf16(av[kt], bh[1][kt], acc1, 0, 0, 0);
    }

    // ---- cross-wave K reduction via LDS ------------------------------------
    *(f32x4*)&red[((wv * 2 + 0) * 64 + lane) * 4] = acc0;
    *(f32x4*)&red[((wv * 2 + 1) * 64 + lane) * 4] = acc1;
    __syncthreads();

    // ---- epilogue -----------------------------------------------------------
    float z0 = 0.f, z1 = 0.f;
#pragma unroll
    for (int w = 0; w < 4; ++w) {
      z0 += red[((w * 2 + ont) * 64 + okb * 16 + oci + 0) * 4 + orr];
      z1 += red[((w * 2 + ont) * 64 + okb * 16 + oci + 1) * 4 + orr];
    }
    float hn0 = 0.5f * tanhf(z0 + uf.x) + 0.5f * hreg[0];
    float hn1 = 0.5f * tanhf(z1 + uf.y) + 0.5f * hreg[1];
    hreg[0] = hn0; hreg[1] = hn1;
    po0 = hn0; po1 = hn1;

    // ---- h store + drain ----------------------------------------------------
    {
      u32 pk = (u32)f2bf(hn0) | ((u32)f2bf(hn1) << 16);
      u32* hdst = (u32*)((char*)Hb + (size_t)((t + 1) & 1) * HB_BYTES
                         + (size_t)grow * 2048 + (c0 + col0) * 2);
      if (xlocal) {
        *hdst = pk;                                   // plain: acks at local L2
      } else {
        (void)__hip_atomic_exchange(hdst, pk, __ATOMIC_RELAXED,
                                    __HIP_MEMORY_SCOPE_AGENT);
      }
    }
    asm volatile("s_waitcnt vmcnt(0)" ::: "memory");  // h committed; out aged
    __syncthreads();

    if (t < T_STEPS - 1) {
      if (tid == 0) {
        if (xlocal) *(volatile u32*)(flags + j) = (u32)(t + 1);
        else        AST(flags + j, (u32)(t + 1));
      }
      // ---- poll: nothing else outstanding now --------------------------------
      if (wv == 0) {
        u32 tgt = (u32)(t + 1);
        if (xlocal) {
          const u32* fp = flags + (lane & 31);
          while (true) {
            u32 v = ALD(fp);
            if (__all((int)(v >= tgt))) break;
          }
          asm volatile("buffer_inv\n\ts_waitcnt vmcnt(0)" ::: "memory");
        } else {
          while (true) {
            u32 v = ALD(flags + (lane & 31));
            if (__all((int)(v >= tgt))) break;
            __builtin_amdgcn_s_sleep(1);
          }
        }
      }
      __syncthreads();
    }
    uf = ufn;
  }
  // flush the final out row (t = 511)
  {
    f32x2 o2; o2.x = po0; o2.y = po1;
    __builtin_nontemporal_store(o2,
        (f32x2*)(out + ((size_t)grow * 512 + (T_STEPS - 1)) * 1024 + c0 + col0));
  }
}

// ============================================================================
extern "C" void kernel_launch(void* const* d_in, const int* in_sizes, int n_in,
                              void* d_out, int out_size, void* d_ws, size_t ws_size,
                              hipStream_t stream) {
  (void)in_sizes; (void)n_in; (void)out_size; (void)ws_size;
  const float* x  = (const float*)d_in[0];   // [32,4,512,64]
  const float* Wi = (const float*)d_in[1];   // [1024,256]
  const float* W  = (const float*)d_in[2];   // [1024,1024]
  float* out = (float*)d_out;                // [32,4,512,1024]

  char* ws  = (char*)d_ws;
  u16*  whi = (u16*)(ws + OFF_WHI);
  float* U  = (float*)(ws + OFF_U);
  u16*  hb  = (u16*)(ws + OFF_HB);
  u32*  bar = (u32*)(ws + OFF_BAR);

  // zero h0 double-buffer + census/claim/flag region (monotonic per launch)
  (void)hipMemsetAsync(ws + OFF_HB, 0, 2 * HB_BYTES + 16384, stream);

  hipLaunchKernelGGL(prep_w, dim3(4, 1024), dim3(256), 0, stream, W, whi);
  hipLaunchKernelGGL(prep_u2, dim3(128, 8), dim3(256), 0, stream, x, Wi, U);
  hipLaunchKernelGGL(esn_scan, dim3(NWG), dim3(TPB), 0, stream,
                     whi, U, hb, out, bar);
}